// Round 6
// baseline (41.095 us; speedup 1.0000x reference)
//
#include <hip/hip_runtime.h>

#define NPTS 16384
#define KS   16                  // stored bf16 k-slots per point (32 B)
#define BT   256                 // 4 waves per block
#define BROWS 256                // rows per block: 4 waves x 2 32-row tiles
#define TSPLIT 4
#define SWEEP (NPTS / TSPLIT)    // 4096 targets per block sweep
#define NTILE (SWEEP / 32)       // 128 32-target tiles
#define NR (NTILE / 2)           // 64 rounds of 2 tiles

typedef __attribute__((ext_vector_type(8)))  short bf16x8;
typedef __attribute__((ext_vector_type(16))) float f32x16;
typedef __attribute__((ext_vector_type(8)))  unsigned short ushort8;

__device__ __forceinline__ unsigned short btrunc(float f) {
    return (unsigned short)(__float_as_uint(f) >> 16);
}
__device__ __forceinline__ float btruncf(float f) {
    return __uint_as_float(__float_as_uint(f) & 0xFFFF0000u);
}

// A-role (source rows):  [-2xh, -2xl, -2xh, -2yh, -2yl, -2yh, -2zh, -2zl, -2zh, 1, 1, 0...]
// B-role (target cols):  [ xh ,  xh ,  xl ,  yh ,  yh ,  yl ,  zh ,  zh ,  zl , qh, ql, 0...]
// A(s).B(t) = -2 s.t + |t|^2   (lo*lo cross terms dropped, ~2^-16 relative)
__global__ void chamfer_pack(const float* __restrict__ s,
                             const float* __restrict__ t,
                             unsigned short* __restrict__ Apack,
                             unsigned short* __restrict__ Bpack,
                             float* __restrict__ sq,
                             unsigned* __restrict__ outinit)
{
    int i = blockIdx.x * blockDim.x + threadIdx.x;
    if (i >= 2 * NPTS) return;
    outinit[i] = 0x7F7F7F7Fu;            // huge positive float; out_size == 2*NPTS
    int cloud = i >> 14;
    int p = i & (NPTS - 1);
    const float* base = cloud ? t : s;
    float x = base[3 * p], y = base[3 * p + 1], z = base[3 * p + 2];

    float xh = btruncf(x), yh = btruncf(y), zh = btruncf(z);
    float xl = x - xh, yl = y - yh, zl = z - zh;
    float q = x * x + y * y + z * z;
    float qh = btruncf(q), ql = q - qh;

    const unsigned short one = btrunc(1.0f);
    ushort8 A0 = { btrunc(-2.f * xh), btrunc(-2.f * xl), btrunc(-2.f * xh),
                   btrunc(-2.f * yh), btrunc(-2.f * yl), btrunc(-2.f * yh),
                   btrunc(-2.f * zh), btrunc(-2.f * zl) };
    ushort8 A1 = { btrunc(-2.f * zh), one, one, 0, 0, 0, 0, 0 };
    ushort8 B0 = { btrunc(xh), btrunc(xh), btrunc(xl),
                   btrunc(yh), btrunc(yh), btrunc(yl),
                   btrunc(zh), btrunc(zh) };
    ushort8 B1 = { btrunc(zl), btrunc(qh), btrunc(ql), 0, 0, 0, 0, 0 };

    *(ushort8*)(Apack + (size_t)i * KS)     = A0;
    *(ushort8*)(Apack + (size_t)i * KS + 8) = A1;
    *(ushort8*)(Bpack + (size_t)i * KS)     = B0;
    *(ushort8*)(Bpack + (size_t)i * KS + 8) = B1;
    sq[i] = q;
}

// grid = (NPTS/BROWS=64, TSPLIT=4, 2). 2 blocks/CU, 256-VGPR budget.
// Per round: 2 B tiles x 2 row-tiles = 4 MFMA + 32 min3; rotating depth-2-round prefetch.
__global__ __launch_bounds__(BT, 2)
void chamfer_mfma(const unsigned short* __restrict__ Apack,
                  const unsigned short* __restrict__ Bpack,
                  const float* __restrict__ sq,
                  unsigned* __restrict__ out)
{
    const int dir = blockIdx.z;
    const unsigned short* A = Apack + (size_t)(dir ? NPTS : 0) * KS;
    const unsigned short* B = Bpack + (size_t)(dir ? 0 : NPTS) * KS;
    const float* s2 = sq + (dir ? NPTS : 0);
    unsigned* o = out + dir * NPTS;

    const int lane = threadIdx.x & 63;
    const int wv   = threadIdx.x >> 6;
    const int n32  = lane & 31;
    const int kh   = lane >> 5;         // k-slice half (0: k0..7, 1: k8..15)

    const int rbase = blockIdx.x * BROWS + wv * 64;

    const bf16x8 a0 = *(const bf16x8*)(A + (size_t)(rbase + n32) * KS + kh * 8);
    const bf16x8 a1 = *(const bf16x8*)(A + (size_t)(rbase + 32 + n32) * KS + kh * 8);

    f32x16 mn0, mn1, zc;
#pragma unroll
    for (int r = 0; r < 16; ++r) { mn0[r] = 1e30f; mn1[r] = 1e30f; zc[r] = 0.0f; }

    const unsigned short* Bl = B + (size_t)(blockIdx.y * SWEEP + n32) * KS + kh * 8;
#define BTILE(t) (*(const bf16x8*)(Bl + (size_t)(t) * 32 * KS))

    bf16x8 b0 = BTILE(0), b1 = BTILE(1);
    bf16x8 n0 = BTILE(2), n1 = BTILE(3);

#pragma unroll 2
    for (int r = 0; r < NR; ++r) {
        int tp = (2 * r + 4 < NTILE) ? 2 * r + 4 : NTILE - 2;   // clamped prefetch idx
        bf16x8 p0 = BTILE(tp);
        bf16x8 p1 = BTILE(tp + 1);

        f32x16 c00 = __builtin_amdgcn_mfma_f32_32x32x16_bf16(a0, b0, zc, 0, 0, 0);
        f32x16 c01 = __builtin_amdgcn_mfma_f32_32x32x16_bf16(a0, b1, zc, 0, 0, 0);
        f32x16 c10 = __builtin_amdgcn_mfma_f32_32x32x16_bf16(a1, b0, zc, 0, 0, 0);
        f32x16 c11 = __builtin_amdgcn_mfma_f32_32x32x16_bf16(a1, b1, zc, 0, 0, 0);
#pragma unroll
        for (int k = 0; k < 16; ++k)
            mn0[k] = fminf(fminf(mn0[k], c00[k]), c01[k]);       // -> v_min3_f32
#pragma unroll
        for (int k = 0; k < 16; ++k)
            mn1[k] = fminf(fminf(mn1[k], c10[k]), c11[k]);

        b0 = n0; b1 = n1; n0 = p0; n1 = p1;                      // rotate (renamed by unroll)
    }

    // column reduce across the 32 lanes of each half-wave group
#pragma unroll
    for (int r = 0; r < 16; ++r) {
        float v0 = mn0[r], v1 = mn1[r];
        v0 = fminf(v0, __shfl_xor(v0, 1, 32));  v1 = fminf(v1, __shfl_xor(v1, 1, 32));
        v0 = fminf(v0, __shfl_xor(v0, 2, 32));  v1 = fminf(v1, __shfl_xor(v1, 2, 32));
        v0 = fminf(v0, __shfl_xor(v0, 4, 32));  v1 = fminf(v1, __shfl_xor(v1, 4, 32));
        v0 = fminf(v0, __shfl_xor(v0, 8, 32));  v1 = fminf(v1, __shfl_xor(v1, 8, 32));
        v0 = fminf(v0, __shfl_xor(v0, 16, 32)); v1 = fminf(v1, __shfl_xor(v1, 16, 32));
        mn0[r] = v0; mn1[r] = v1;
    }

    if (n32 == 0) {
        // C/D map (32x32, r2/r3-verified): col = lane&31, row = (r&3) + 8*(r>>2) + 4*kh
#pragma unroll
        for (int r = 0; r < 16; ++r) {
            int row0 = rbase + (r & 3) + 8 * (r >> 2) + 4 * kh;
            float d0 = fmaxf(mn0[r] + s2[row0], 0.0f);
            atomicMin(&o[row0], __float_as_uint(d0));
            int row1 = row0 + 32;
            float d1 = fmaxf(mn1[r] + s2[row1], 0.0f);
            atomicMin(&o[row1], __float_as_uint(d1));
        }
    }
#undef BTILE
}

extern "C" void kernel_launch(void* const* d_in, const int* in_sizes, int n_in,
                              void* d_out, int out_size, void* d_ws, size_t ws_size,
                              hipStream_t stream) {
    const float* s = (const float*)d_in[0];
    const float* t = (const float*)d_in[1];

    unsigned short* Apack = (unsigned short*)d_ws;                 // 1 MB
    unsigned short* Bpack = Apack + (size_t)2 * NPTS * KS;         // 1 MB
    float* sq = (float*)(Bpack + (size_t)2 * NPTS * KS);           // 128 KB

    chamfer_pack<<<(2 * NPTS + BT - 1) / BT, BT, 0, stream>>>(
        s, t, Apack, Bpack, sq, (unsigned*)d_out);

    dim3 grid(NPTS / BROWS, TSPLIT, 2);
    chamfer_mfma<<<grid, BT, 0, stream>>>(Apack, Bpack, sq, (unsigned*)d_out);
}